// Round 1
// baseline (718.976 us; speedup 1.0000x reference)
//
#include <hip/hip_runtime.h>
#include <stdint.h>

#define D 128
#define E_EDGES 600000
#define N_USER_C 100000
#define N_ITEM_C 50000
#define TILE_E 64
#define NEG_SLOPE 0.01f
#define LN_EPS 1e-5f

typedef __attribute__((ext_vector_type(8))) short bf16x8;
typedef __attribute__((ext_vector_type(4))) float f32x4;

// fp32 -> bf16 round-to-nearest-even
__device__ inline short f2bf(float f) {
    uint32_t u = __builtin_bit_cast(uint32_t, f);
    u += 0x7fffu + ((u >> 16) & 1u);
    return (short)(u >> 16);
}

__device__ inline uint32_t pack2(short a, short b) {
    return (uint32_t)(uint16_t)a | ((uint32_t)(uint16_t)b << 16);
}

// One relation: for each edge e, m = LeakyReLU((xsrc[src[e]] * xdst[dst[e]]) @ W + b)
// scatter-add m into agg[dst[e]].
// Block = 256 threads (4 waves). Each block stages W^T (bf16) in LDS once, then
// loops over 64-edge tiles: stage P = xs*xd products (bf16) in LDS, MFMA, atomicAdd.
#define LDPAD 136   // 128 + 8 bf16 pad: rows stay 16B-aligned, banks 2-way max

__global__ __launch_bounds__(256, 3) void ngcf_edge(
    const float* __restrict__ xsrc, const float* __restrict__ xdst,
    const float* __restrict__ W, const float* __restrict__ bias,
    const int* __restrict__ src_idx, const int* __restrict__ dst_idx,
    float* __restrict__ agg, int n_tiles)
{
    __shared__ short Wt[128 * LDPAD];   // Wt[n][k] = W[k][n], bf16
    __shared__ short Pl[TILE_E * LDPAD]; // P[e][k] bf16
    __shared__ float bias_s[D];
    __shared__ int   dst_s[TILE_E];

    const int t = threadIdx.x;

    // Stage W^T (transpose + convert), coalesced global reads
    for (int i = t; i < 128 * 128; i += 256) {
        int k = i >> 7, n = i & 127;
        Wt[n * LDPAD + k] = f2bf(W[i]);
    }
    if (t < D) bias_s[t] = bias[t];
    __syncthreads();

    const int wv   = t >> 6;       // wave 0..3
    const int l    = t & 63;
    const int lo16 = l & 15;
    const int quad = l >> 4;       // 0..3

    const int e = t >> 2;          // edge slot 0..63 (staging role)
    const int q = t & 3;           // quarter of the row

    for (int tile = blockIdx.x; tile < n_tiles; tile += gridDim.x) {
        const int ebase = tile * TILE_E;

        // ---- stage P: 4 threads per edge, 32 floats each ----
        const int ge = ebase + e;
        const int si = src_idx[ge];
        const int di = dst_idx[ge];
        if (q == 0) dst_s[e] = di;
        const float4* ps = (const float4*)(xsrc + (size_t)si * D) + q * 8;
        const float4* pd = (const float4*)(xdst + (size_t)di * D) + q * 8;
        uint32_t* prow = (uint32_t*)&Pl[e * LDPAD + q * 32];
        #pragma unroll
        for (int i = 0; i < 8; i++) {
            float4 a = ps[i];
            float4 b = pd[i];
            prow[i * 2 + 0] = pack2(f2bf(a.x * b.x), f2bf(a.y * b.y));
            prow[i * 2 + 1] = pack2(f2bf(a.z * b.z), f2bf(a.w * b.w));
        }
        __syncthreads();

        // ---- MFMA: wave wv computes edges [wv*16, wv*16+16) x all 128 cols ----
        f32x4 acc[8];
        #pragma unroll
        for (int n = 0; n < 8; n++) acc[n] = (f32x4){0.f, 0.f, 0.f, 0.f};

        #pragma unroll
        for (int kt = 0; kt < 4; kt++) {
            bf16x8 afrag = *(const bf16x8*)&Pl[(wv * 16 + lo16) * LDPAD + kt * 32 + quad * 8];
            #pragma unroll
            for (int n = 0; n < 8; n++) {
                bf16x8 bfrag = *(const bf16x8*)&Wt[(n * 16 + lo16) * LDPAD + kt * 32 + quad * 8];
                acc[n] = __builtin_amdgcn_mfma_f32_16x16x32_bf16(afrag, bfrag, acc[n], 0, 0, 0);
            }
        }

        // ---- epilogue: bias + LeakyReLU + scatter atomicAdd ----
        #pragma unroll
        for (int n = 0; n < 8; n++) {
            const int col = n * 16 + lo16;
            const float bb = bias_s[col];
            #pragma unroll
            for (int r = 0; r < 4; r++) {
                const int m = wv * 16 + quad * 4 + r;
                float v = acc[n][r] + bb;
                v = v > 0.f ? v : NEG_SLOPE * v;
                atomicAdd(&agg[(size_t)dst_s[m] * D + col], v);
            }
        }
        __syncthreads();  // protect Pl/dst_s before next tile overwrites
    }
}

// In-place LayerNorm(mode=node) + ReLU over rows of data. Rows < n_user use
// user params, else item params. One wave per row, 2 floats per lane.
__global__ __launch_bounds__(256) void ln_relu(
    float* __restrict__ data,
    const float* __restrict__ lnw_u, const float* __restrict__ lnb_u,
    const float* __restrict__ lnw_i, const float* __restrict__ lnb_i,
    int n_user, int n_total)
{
    const int row = blockIdx.x * 4 + (threadIdx.x >> 6);
    if (row >= n_total) return;
    const int l = threadIdx.x & 63;

    float* rp = data + (size_t)row * D;
    float2 v = *(float2*)(rp + l * 2);
    float s  = v.x + v.y;
    float sq = v.x * v.x + v.y * v.y;
    #pragma unroll
    for (int off = 32; off > 0; off >>= 1) {
        s  += __shfl_xor(s, off);
        sq += __shfl_xor(sq, off);
    }
    const float mu  = s * (1.0f / 128.0f);
    const float var = sq * (1.0f / 128.0f) - mu * mu;
    const float rs  = rsqrtf(var + LN_EPS);

    const float* wgt = (row < n_user) ? lnw_u : lnw_i;
    const float* bia = (row < n_user) ? lnb_u : lnb_i;
    float2 wv2 = *(const float2*)(wgt + l * 2);
    float2 bv2 = *(const float2*)(bia + l * 2);

    float o0 = (v.x - mu) * rs * wv2.x + bv2.x;
    float o1 = (v.y - mu) * rs * wv2.y + bv2.y;
    o0 = fmaxf(o0, 0.f);
    o1 = fmaxf(o1, 0.f);
    *(float2*)(rp + l * 2) = make_float2(o0, o1);
}

extern "C" void kernel_launch(void* const* d_in, const int* in_sizes, int n_in,
                              void* d_out, int out_size, void* d_ws, size_t ws_size,
                              hipStream_t stream) {
    const float* x_user    = (const float*)d_in[0];
    const float* x_item    = (const float*)d_in[1];
    const float* W_ui      = (const float*)d_in[2];
    const float* b_ui      = (const float*)d_in[3];
    const float* W_iu      = (const float*)d_in[4];
    const float* b_iu      = (const float*)d_in[5];
    const float* ln_w_user = (const float*)d_in[6];
    const float* ln_b_user = (const float*)d_in[7];
    const float* ln_w_item = (const float*)d_in[8];
    const float* ln_b_item = (const float*)d_in[9];
    const int* esrc_ui = (const int*)d_in[10];
    const int* edst_ui = (const int*)d_in[11];
    const int* esrc_iu = (const int*)d_in[12];
    const int* edst_iu = (const int*)d_in[13];

    float* out = (float*)d_out;
    float* agg_user = out;                          // N_USER x D
    float* agg_item = out + (size_t)N_USER_C * D;   // N_ITEM x D

    // Aggregation buffers live in d_out; zero them (harness poisons with 0xAA).
    hipMemsetAsync(d_out, 0, (size_t)out_size * sizeof(float), stream);

    const int n_tiles = E_EDGES / TILE_E;  // 9375
    dim3 blk(256);
    dim3 grid(768);  // persistent: 3 blocks/CU at ~53 KB LDS

    // relation user->item: messages aggregated at items
    ngcf_edge<<<grid, blk, 0, stream>>>(x_user, x_item, W_ui, b_ui,
                                        esrc_ui, edst_ui, agg_item, n_tiles);
    // relation item->user: messages aggregated at users
    ngcf_edge<<<grid, blk, 0, stream>>>(x_item, x_user, W_iu, b_iu,
                                        esrc_iu, edst_iu, agg_user, n_tiles);

    const int n_total = N_USER_C + N_ITEM_C;
    ln_relu<<<dim3((n_total + 3) / 4), blk, 0, stream>>>(
        out, ln_w_user, ln_b_user, ln_w_item, ln_b_item, N_USER_C, n_total);
}